// Round 3
// baseline (131.993 us; speedup 1.0000x reference)
//
#include <hip/hip_runtime.h>

// GatedBlock: RS = [(256,0),(128,1),(64,2),(32,3)]
// SIZE_OUT = 1184, N_GATES = 224, ROW_IN = 1408
// out col c: [0,256) relu | [256,640) *sig(g[(c-256)/3]) |
//            [640,960) *sig(g[128+(c-640)/5]) | [960,1184) *sig(g[192+(c-960)/7])
// gates at input row offset 1184. All boundaries %4==0.

#define SIZE_OUT 1184
#define ROW_IN   1408
#define N_F4     296   // SIZE_OUT/4
#define N_GATES  224
#define G_F4     56    // N_GATES/4
#define ROWS_PB  16    // rows per block

typedef float f32x4 __attribute__((ext_vector_type(4)));

__global__ __launch_bounds__(256) void gated_block_kernel(
    const float* __restrict__ in, float* __restrict__ out)
{
    __shared__ float s_sig[ROWS_PB][N_GATES];

    const long long row0 = (long long)blockIdx.x * ROWS_PB;
    const int tid = (int)threadIdx.x;

    // Phase 1: stage sigmoid(gates) for 16 rows into LDS.
    // Gates are read exactly once chip-wide -> nontemporal too.
    #pragma unroll
    for (int k = 0; k < (ROWS_PB * G_F4 + 255) / 256; ++k) {
        int i = tid + k * 256;
        if (i < ROWS_PB * G_F4) {               // 896 = 3.5*256; tail wave-uniform
            int r = i / G_F4;                   // const-div magic
            int q = i - r * G_F4;
            const float* g = in + (row0 + r) * ROW_IN + SIZE_OUT;
            f32x4 gv = __builtin_nontemporal_load(
                reinterpret_cast<const f32x4*>(g) + q);
            #pragma unroll
            for (int j = 0; j < 4; ++j)
                s_sig[r][q * 4 + j] = 1.0f / (1.0f + __expf(-gv[j]));
        }
    }
    __syncthreads();

    // Phase 2: stream the data region, 2 VMEM per float4.
    for (int i = tid; i < ROWS_PB * N_F4; i += 256) {   // 4736 = 18.5*256
        int r  = i / N_F4;                      // const-div magic
        int c4 = i - r * N_F4;
        long long row = row0 + r;

        f32x4 v = __builtin_nontemporal_load(
            reinterpret_cast<const f32x4*>(in + row * ROW_IN) + c4);

        if (c4 < 64) {
            #pragma unroll
            for (int j = 0; j < 4; ++j) v[j] = fmaxf(v[j], 0.0f);
        } else {
            int c = c4 * 4;
            int off, d, gbase;
            if (c4 < 160)      { off = c - 256; d = 3; gbase = 0;   }
            else if (c4 < 240) { off = c - 640; d = 5; gbase = 128; }
            else               { off = c - 960; d = 7; gbase = 192; }
            #pragma unroll
            for (int j = 0; j < 4; ++j) {
                int g = gbase + (off + j) / d;  // const-div magic
                v[j] *= s_sig[r][g];
            }
        }
        __builtin_nontemporal_store(v,
            reinterpret_cast<f32x4*>(out + row * SIZE_OUT) + c4);
    }
}

extern "C" void kernel_launch(void* const* d_in, const int* in_sizes, int n_in,
                              void* d_out, int out_size, void* d_ws, size_t ws_size,
                              hipStream_t stream)
{
    const float* in = (const float*)d_in[0];
    float* out = (float*)d_out;

    // 65536 rows / 16 rows-per-block = 4096 blocks, no remainder
    int grid = (out_size / SIZE_OUT) / ROWS_PB;
    gated_block_kernel<<<grid, 256, 0, stream>>>(in, out);
}

// Round 4
// 120.273 us; speedup vs baseline: 1.0974x; 1.0974x over previous
//
#include <hip/hip_runtime.h>

// GatedBlock: RS = [(256,0),(128,1),(64,2),(32,3)]
// SIZE_OUT = 1184, N_GATES = 224, ROW_IN = 1408
// out col c: [0,256) relu | [256,640) *sig(g[(c-256)/3]) |
//            [640,960) *sig(g[128+(c-640)/5]) | [960,1184) *sig(g[192+(c-960)/7])
// gates at input row offset 1184. All boundaries %4==0 -> each output
// float4 stays in one segment.
//
// R3 post-mortem: LDS gate staging REGRESSED (120->132us): barrier + lgkmcnt
// on the critical path; scalar gate loads are L1-resident and free.
// This is the R2 structure (120.2us = 90% of 6.29 TB/s copy ceiling)
// + 2x manual unroll for one extra outstanding load per thread.

#define SIZE_OUT 1184
#define ROW_IN   1408
#define N_F4     296   // SIZE_OUT/4

typedef float f32x4 __attribute__((ext_vector_type(4)));

__device__ __forceinline__ float fast_sigmoid(float x) {
    return 1.0f / (1.0f + __expf(-x));
}

__device__ __forceinline__ void process(const float* __restrict__ in,
                                        float* __restrict__ out, int idx)
{
    unsigned row = (unsigned)idx / N_F4;        // 32-bit magic mul
    int c4  = idx - (int)(row * N_F4);
    const float* __restrict__ rin = in + (long long)row * ROW_IN;

    f32x4 v = __builtin_nontemporal_load(
        reinterpret_cast<const f32x4*>(rin) + c4);

    if (c4 < 64) {
        #pragma unroll
        for (int j = 0; j < 4; ++j) v[j] = fmaxf(v[j], 0.0f);
    } else {
        const float* __restrict__ gates = rin + SIZE_OUT;
        int c = c4 * 4;
        int off, d, gbase;
        if (c4 < 160)      { off = c - 256; d = 3; gbase = 0;   }
        else if (c4 < 240) { off = c - 640; d = 5; gbase = 128; }
        else               { off = c - 960; d = 7; gbase = 192; }
        #pragma unroll
        for (int j = 0; j < 4; ++j) {
            int g = gbase + (off + j) / d;      // const-div magic
            v[j] *= fast_sigmoid(gates[g]);     // gates: cached (reused 3-7x)
        }
    }
    __builtin_nontemporal_store(v, reinterpret_cast<f32x4*>(out) + idx);
}

__global__ __launch_bounds__(256) void gated_block_kernel(
    const float* __restrict__ in, float* __restrict__ out, int total4)
{
    int stride = gridDim.x * blockDim.x;
    int idx = blockIdx.x * blockDim.x + threadIdx.x;

    // unroll x2: two independent nt loads in flight per trip
    for (; idx + stride < total4; idx += 2 * stride) {
        process(in, out, idx);
        process(in, out, idx + stride);
    }
    if (idx < total4) process(in, out, idx);
}

extern "C" void kernel_launch(void* const* d_in, const int* in_sizes, int n_in,
                              void* d_out, int out_size, void* d_ws, size_t ws_size,
                              hipStream_t stream)
{
    const float* in = (const float*)d_in[0];
    float* out = (float*)d_out;

    int total4 = out_size / 4;   // 65536 * 296 = 19,398,656
    int block = 256;
    long long want = ((long long)total4 + block - 1) / block;
    int grid = (int)(want < 4096 ? want : 4096);

    gated_block_kernel<<<grid, block, 0, stream>>>(in, out, total4);
}